// Round 1
// baseline (1433.618 us; speedup 1.0000x reference)
//
#include <hip/hip_runtime.h>
#include <hip/hip_bf16.h>

// GCN sparse aggregation: out[rows[e], :] += vals[e] * embeds[cols[e], :]
// E = 1.6M, N = 100K, D = 64, fp32.
//
// Baseline strategy (round 1): direct scatter-add with fp32 atomics.
//  - 16 lanes cooperate on one edge; each lane owns one float4 (4 feats).
//  - Gather of embeds[col] is a coalesced 256B read per edge.
//  - 4 atomicAdds per lane -> 64 per edge -> 102.4M total.
// d_out is poisoned 0xAA by the harness before every launch -> zero it
// with hipMemsetAsync (stream-ordered, graph-capture safe).

#define D_FEAT 64

__global__ __launch_bounds__(256) void gcn_scatter_kernel(
    const int* __restrict__ rows,
    const int* __restrict__ cols,
    const float* __restrict__ vals,
    const float* __restrict__ embeds,
    float* __restrict__ out,
    int n_edges)
{
    int gtid = blockIdx.x * blockDim.x + threadIdx.x;
    int e = gtid >> 4;            // 16 lanes per edge
    if (e >= n_edges) return;
    int lane4 = gtid & 15;        // which float4 of the 64-feat row

    int row = rows[e];
    int col = cols[e];
    float v = vals[e];

    const float4* ep = reinterpret_cast<const float4*>(embeds + (size_t)col * D_FEAT);
    float4 m = ep[lane4];

    float* op = out + (size_t)row * D_FEAT + lane4 * 4;
    atomicAdd(op + 0, v * m.x);
    atomicAdd(op + 1, v * m.y);
    atomicAdd(op + 2, v * m.z);
    atomicAdd(op + 3, v * m.w);
}

extern "C" void kernel_launch(void* const* d_in, const int* in_sizes, int n_in,
                              void* d_out, int out_size, void* d_ws, size_t ws_size,
                              hipStream_t stream) {
    const int*   rows   = (const int*)d_in[0];
    const int*   cols   = (const int*)d_in[1];
    const float* vals   = (const float*)d_in[2];
    const float* embeds = (const float*)d_in[3];
    // d_in[4] = n_nodes scalar (unused on device; out_size = n_nodes * 64)

    float* out = (float*)d_out;
    int n_edges = in_sizes[0];

    // Zero the output (harness re-poisons it with 0xAA before every launch).
    hipMemsetAsync(out, 0, (size_t)out_size * sizeof(float), stream);

    // 16 threads per edge.
    long long total_threads = (long long)n_edges * 16;
    int block = 256;
    int grid = (int)((total_threads + block - 1) / block);
    gcn_scatter_kernel<<<grid, block, 0, stream>>>(rows, cols, vals, embeds, out, n_edges);
}

// Round 2
// 356.036 us; speedup vs baseline: 4.0266x; 4.0266x over previous
//
#include <hip/hip_runtime.h>
#include <hip/hip_bf16.h>

// GCN sparse aggregation: out[rows[e], :] += vals[e] * embeds[cols[e], :]
// E = 1.6M, N = 100K, D = 64, fp32.
//
// Round 2 strategy: per-launch counting-sort of edges by destination row,
// then atomic-free segmented aggregation (one wave per output row).
// Round-1 evidence: 102.4M scalar fp32 atomics caused WRITE_SIZE=1.6GB
// (16 B write-through per atomic, 64x amplification) and 1350 us. The
// data-movement floor is ~50 MB write + ~200 MB fetch => O(100 us).
//
// Pipeline (all per-launch, since d_ws is re-poisoned):
//  K0 memset: deg[N] + cursor = 0
//  K1 histogram: deg[rows[e]]++ (int atomics, avg contention 16)
//  K2 alloc: per-row region start via wave-aggregated global cursor
//            (off[r] = cur[r] = base; only ~1.6K same-address atomics)
//  K3 scatter: p = cur[rows[e]]++; sorted[p] = {cols[e], vals[e]} (8B store)
//  K4 aggregate: wave w owns row r; lane owns one feature; for each edge in
//            segment: coalesced 256B gather of embeds[col], fma; one
//            coalesced 256B store of out[r]. Rows with deg=0 write zeros,
//            so no out memset needed.

#define D_FEAT 64

// ---------------- fallback (round-1 atomic path) ----------------
__global__ __launch_bounds__(256) void gcn_scatter_fallback(
    const int* __restrict__ rows, const int* __restrict__ cols,
    const float* __restrict__ vals, const float* __restrict__ embeds,
    float* __restrict__ out, int n_edges)
{
    int gtid = blockIdx.x * blockDim.x + threadIdx.x;
    int e = gtid >> 4;
    if (e >= n_edges) return;
    int lane4 = gtid & 15;
    int row = rows[e]; int col = cols[e]; float v = vals[e];
    const float4* ep = reinterpret_cast<const float4*>(embeds + (size_t)col * D_FEAT);
    float4 m = ep[lane4];
    float* op = out + (size_t)row * D_FEAT + lane4 * 4;
    atomicAdd(op + 0, v * m.x);
    atomicAdd(op + 1, v * m.y);
    atomicAdd(op + 2, v * m.z);
    atomicAdd(op + 3, v * m.w);
}

// ---------------- K1: histogram ----------------
__global__ __launch_bounds__(256) void k_hist(
    const int* __restrict__ rows, int* __restrict__ deg, int n_edges)
{
    int e = blockIdx.x * blockDim.x + threadIdx.x;
    if (e >= n_edges) return;
    atomicAdd(&deg[rows[e]], 1);
}

// ---------------- K2: region alloc (wave-aggregated cursor) ----------------
__global__ __launch_bounds__(256) void k_alloc(
    const int* __restrict__ deg, int* __restrict__ off, int* __restrict__ cur,
    int* __restrict__ cursor, int n_nodes)
{
    int r = blockIdx.x * blockDim.x + threadIdx.x;
    int lane = threadIdx.x & 63;
    int d = (r < n_nodes) ? deg[r] : 0;

    // inclusive wave scan over 64 lanes
    int x = d;
    #pragma unroll
    for (int ofs = 1; ofs < 64; ofs <<= 1) {
        int y = __shfl_up(x, ofs, 64);
        if (lane >= ofs) x += y;
    }
    int wavesum = __shfl(x, 63, 64);
    int base = 0;
    if (lane == 63) base = atomicAdd(cursor, wavesum);
    base = __shfl(base, 63, 64);

    if (r < n_nodes) {
        int start = base + x - d;   // exclusive scan position
        off[r] = start;
        cur[r] = start;
    }
}

// ---------------- K3: scatter into row-sorted order ----------------
__global__ __launch_bounds__(256) void k_scatter(
    const int* __restrict__ rows, const int* __restrict__ cols,
    const float* __restrict__ vals, int* __restrict__ cur,
    int2* __restrict__ sorted, int n_edges)
{
    int e = blockIdx.x * blockDim.x + threadIdx.x;
    if (e >= n_edges) return;
    int r = rows[e];
    int p = atomicAdd(&cur[r], 1);
    int2 pk;
    pk.x = cols[e];
    pk.y = __float_as_int(vals[e]);
    sorted[p] = pk;
}

// ---------------- K4: segmented aggregation, one wave per row ----------------
__global__ __launch_bounds__(256) void k_aggregate(
    const int* __restrict__ off, const int* __restrict__ deg,
    const int2* __restrict__ sorted, const float* __restrict__ embeds,
    float* __restrict__ out, int n_nodes)
{
    int row = blockIdx.x * 4 + (threadIdx.x >> 6);   // 4 waves per block
    if (row >= n_nodes) return;
    int lane = threadIdx.x & 63;

    int s = off[row];
    int d = deg[row];
    const int2* sp = sorted + s;

    float acc = 0.0f;
    int j = 0;
    // unroll 4 edges for memory-level parallelism on the gathers
    for (; j + 3 < d; j += 4) {
        int2 e0 = sp[j + 0];
        int2 e1 = sp[j + 1];
        int2 e2 = sp[j + 2];
        int2 e3 = sp[j + 3];
        float m0 = embeds[(size_t)e0.x * D_FEAT + lane];
        float m1 = embeds[(size_t)e1.x * D_FEAT + lane];
        float m2 = embeds[(size_t)e2.x * D_FEAT + lane];
        float m3 = embeds[(size_t)e3.x * D_FEAT + lane];
        acc += __int_as_float(e0.y) * m0;
        acc += __int_as_float(e1.y) * m1;
        acc += __int_as_float(e2.y) * m2;
        acc += __int_as_float(e3.y) * m3;
    }
    for (; j < d; ++j) {
        int2 e0 = sp[j];
        acc += __int_as_float(e0.y) * embeds[(size_t)e0.x * D_FEAT + lane];
    }
    out[(size_t)row * D_FEAT + lane] = acc;
}

extern "C" void kernel_launch(void* const* d_in, const int* in_sizes, int n_in,
                              void* d_out, int out_size, void* d_ws, size_t ws_size,
                              hipStream_t stream) {
    const int*   rows   = (const int*)d_in[0];
    const int*   cols   = (const int*)d_in[1];
    const float* vals   = (const float*)d_in[2];
    const float* embeds = (const float*)d_in[3];

    float* out = (float*)d_out;
    int n_edges = in_sizes[0];
    int n_nodes = out_size / D_FEAT;

    // workspace layout
    // [deg: N ints][cursor: 1 int][off: N ints][cur: N ints][sorted: E int2]
    size_t need = ((size_t)3 * n_nodes + 1) * sizeof(int) + (size_t)n_edges * sizeof(int2);
    if (ws_size < need + 256) {
        // fallback: round-1 atomic path (needs zeroed out)
        hipMemsetAsync(out, 0, (size_t)out_size * sizeof(float), stream);
        long long total_threads = (long long)n_edges * 16;
        int block = 256;
        int grid = (int)((total_threads + block - 1) / block);
        gcn_scatter_fallback<<<grid, block, 0, stream>>>(rows, cols, vals, embeds, out, n_edges);
        return;
    }

    int*  deg    = (int*)d_ws;
    int*  cursor = deg + n_nodes;
    int*  off    = cursor + 1;
    int*  cur    = off + n_nodes;
    int2* sorted = (int2*)(cur + n_nodes);   // int2 is 8-byte; offset is multiple of 4...
    // ensure 8-byte alignment of sorted
    {
        uintptr_t p = (uintptr_t)sorted;
        sorted = (int2*)((p + 7) & ~(uintptr_t)7);
    }

    // K0: zero deg + cursor (adjacent)
    hipMemsetAsync(deg, 0, ((size_t)n_nodes + 1) * sizeof(int), stream);

    int block = 256;
    int gridE = (n_edges + block - 1) / block;
    int gridN = (n_nodes + block - 1) / block;
    int gridA = (n_nodes + 3) / 4;   // 4 waves (rows) per block in K4

    k_hist<<<gridE, block, 0, stream>>>(rows, deg, n_edges);
    k_alloc<<<gridN, block, 0, stream>>>(deg, off, cur, cursor, n_nodes);
    k_scatter<<<gridE, block, 0, stream>>>(rows, cols, vals, cur, sorted, n_edges);
    k_aggregate<<<gridA, block, 0, stream>>>(off, deg, sorted, embeds, out, n_nodes);
}